// Round 1
// baseline (1864.821 us; speedup 1.0000x reference)
//
#include <hip/hip_runtime.h>
#include <hip/hip_bf16.h>
#include <cstdint>

// Problem constants
#define B_    128
#define SEQ   2048
#define WIN   32
#define RES   512
#define TSEG  64      // SEQ/WIN
#define WASH  4
#define KOUT  30720   // (TSEG-WASH)*RES
#define NOUT  8192    // PRED_SEG*RES
#define PSEG  16

typedef __bf16 bf16_t;
typedef __bf16 bf16x8 __attribute__((ext_vector_type(8)));
typedef float  f32x4  __attribute__((ext_vector_type(4)));

__device__ __forceinline__ float blo(unsigned u) { return __builtin_bit_cast(float, u << 16); }
__device__ __forceinline__ float bhi(unsigned u) { return __builtin_bit_cast(float, u & 0xffff0000u); }

// ---------------------------------------------------------------------------
// Kernel 1: pack W_res (fp32 [j][k]) -> bf16 W_res^T blocked [k/8][j][8]
// scan reads uint4 at index kb*512+j -> 8 k-values for column j, coalesced.
// ---------------------------------------------------------------------------
__global__ __launch_bounds__(256) void wpack_kernel(const float* __restrict__ Wres,
                                                    bf16_t* __restrict__ Wp) {
    int g = blockIdx.x * 256 + threadIdx.x;   // 0..32767 = (kb, j)
    int kb = g >> 9, j = g & 511;
    const float4* src = (const float4*)(Wres + j * RES + kb * 8);
    float4 a = src[0], b = src[1];
    bf16x8 v;
    v[0] = (bf16_t)a.x; v[1] = (bf16_t)a.y; v[2] = (bf16_t)a.z; v[3] = (bf16_t)a.w;
    v[4] = (bf16_t)b.x; v[5] = (bf16_t)b.y; v[6] = (bf16_t)b.z; v[7] = (bf16_t)b.w;
    ((bf16x8*)Wp)[g] = v;                     // coalesced 16B stores
}

// ---------------------------------------------------------------------------
// Kernel 2: Xproj[b][t][j] = sum_w x[b][t*32+w] * W_in[j][w]   (fp32)
// grid 512 = 128 b * 2 jhalf * 2 thalf
// ---------------------------------------------------------------------------
__global__ __launch_bounds__(256) void xproj_kernel(const float* __restrict__ x,
                                                    const float* __restrict__ Win,
                                                    float* __restrict__ Xp) {
    __shared__ __align__(16) float Wn[256 * 36];   // 256 j-rows, padded stride 36
    __shared__ __align__(16) float xs[1024];
    int tid = threadIdx.x;
    int wid = blockIdx.x;
    int b = wid >> 2, jh = (wid >> 1) & 1, th = wid & 1;
    int j0 = jh * 256;
    #pragma unroll
    for (int i = 0; i < 32; ++i) {
        int f = i * 256 + tid; int j = f >> 5, w = f & 31;
        Wn[j * 36 + w] = Win[(j0 + j) * WIN + w];
    }
    #pragma unroll
    for (int i = 0; i < 4; ++i) {
        int f = i * 256 + tid;
        xs[f] = x[b * SEQ + th * 1024 + f];
    }
    __syncthreads();
    const float4* wr = (const float4*)&Wn[tid * 36];
    for (int tt = 0; tt < 32; ++tt) {
        const float4* xr = (const float4*)&xs[tt * 32];
        float acc = 0.f;
        #pragma unroll
        for (int w4 = 0; w4 < 8; ++w4) {
            float4 wv = wr[w4]; float4 xv = xr[w4];
            acc += xv.x * wv.x + xv.y * wv.y + xv.z * wv.z + xv.w * wv.w;
        }
        int t = th * 32 + tt;
        Xp[(b * TSEG + t) * RES + j0 + tid] = acc;
    }
}

// ---------------------------------------------------------------------------
// Kernel 3: ESN scan. One WG per batch row; h[512] fp32 in LDS; 64 steps.
// W_res^T streamed from L2 as packed bf16; fp32 accumulate; tanh; write
// Hout (bf16) for t >= WASH.
// ---------------------------------------------------------------------------
__global__ __launch_bounds__(256) void scan_kernel(const float* __restrict__ Xp,
                                                   const bf16_t* __restrict__ Wp,
                                                   bf16_t* __restrict__ Hout) {
    __shared__ __align__(16) float hl[RES];
    int tid = threadIdx.x, b = blockIdx.x;
    hl[tid] = 0.f; hl[tid + 256] = 0.f;
    __syncthreads();
    const uint4* wp = (const uint4*)Wp;
    for (int t = 0; t < TSEG; ++t) {
        float acc0 = Xp[(b * TSEG + t) * RES + tid];
        float acc1 = Xp[(b * TSEG + t) * RES + tid + 256];
        #pragma unroll 4
        for (int kb = 0; kb < 64; ++kb) {
            float4 h0 = ((const float4*)hl)[kb * 2];       // broadcast
            float4 h1 = ((const float4*)hl)[kb * 2 + 1];   // broadcast
            uint4 w0 = wp[kb * 512 + tid];                 // col tid, k=kb*8..+7
            uint4 w1 = wp[kb * 512 + tid + 256];           // col tid+256
            acc0 += h0.x * blo(w0.x) + h0.y * bhi(w0.x)
                  + h0.z * blo(w0.y) + h0.w * bhi(w0.y)
                  + h1.x * blo(w0.z) + h1.y * bhi(w0.z)
                  + h1.z * blo(w0.w) + h1.w * bhi(w0.w);
            acc1 += h0.x * blo(w1.x) + h0.y * bhi(w1.x)
                  + h0.z * blo(w1.y) + h0.w * bhi(w1.y)
                  + h1.x * blo(w1.z) + h1.y * bhi(w1.z)
                  + h1.z * blo(w1.w) + h1.w * bhi(w1.w);
        }
        __syncthreads();                 // all reads of h done
        float v0 = tanhf(acc0), v1 = tanhf(acc1);
        hl[tid] = v0; hl[tid + 256] = v1;
        if (t >= WASH) {
            int off = b * KOUT + (t - WASH) * RES;
            Hout[off + tid] = (bf16_t)v0;
            Hout[off + tid + 256] = (bf16_t)v1;
        }
        __syncthreads();                 // h updated before next step
    }
}

// ---------------------------------------------------------------------------
// Kernel 4: readout GEMM  part[ks][128][8192] partial = Hout_bf16 @ Wro^T
// 256 WGs = 64 n-blocks (128 cols) x 4 k-splits (7680 each). BK=32.
// fp32 Wro converted to bf16 in registers during LDS staging (no extra HBM).
// mfma_f32_16x16x32_bf16, 2 M-tiles x 8 N-tiles per wave. Register prefetch.
// ---------------------------------------------------------------------------
__global__ __launch_bounds__(256) void readout_kernel(const bf16_t* __restrict__ Hout,
                                                      const float* __restrict__ Wro,
                                                      float* __restrict__ part) {
    __shared__ __align__(16) bf16_t Al[128 * 40];   // 128 rows, padded stride 40 (80B)
    __shared__ __align__(16) bf16_t Wl[128 * 40];
    int tid = threadIdx.x;
    int nb = blockIdx.x & 63, ks = blockIdx.x >> 6;
    int n0 = nb * 128;
    int k0 = ks * 7680;
    int row = tid >> 1, half = tid & 1;
    int wave = tid >> 6, lane = tid & 63;
    int lm = lane & 15, lq = lane >> 4;
    int mbase = wave * 32;

    f32x4 acc[2][8];
    #pragma unroll
    for (int mt = 0; mt < 2; ++mt)
        #pragma unroll
        for (int nt = 0; nt < 8; ++nt)
            acc[mt][nt] = (f32x4){0.f, 0.f, 0.f, 0.f};

    const bf16_t* Ag = Hout + (int64_t)row * KOUT + k0 + half * 16;
    const float*  Wg = Wro + (int64_t)(n0 + row) * KOUT + k0 + half * 16;

    // prefetch iteration 0
    uint4  a0 = ((const uint4*)Ag)[0];
    uint4  a1 = ((const uint4*)Ag)[1];
    float4 f0 = ((const float4*)Wg)[0];
    float4 f1 = ((const float4*)Wg)[1];
    float4 f2 = ((const float4*)Wg)[2];
    float4 f3 = ((const float4*)Wg)[3];

    int ldst = row * 40 + half * 16;
    for (int it = 0; it < 240; ++it) {
        __syncthreads();                     // prior iteration's LDS reads done
        *(uint4*)&Al[ldst] = a0;
        *(uint4*)&Al[ldst + 8] = a1;
        bf16x8 wv0, wv1;
        wv0[0] = (bf16_t)f0.x; wv0[1] = (bf16_t)f0.y; wv0[2] = (bf16_t)f0.z; wv0[3] = (bf16_t)f0.w;
        wv0[4] = (bf16_t)f1.x; wv0[5] = (bf16_t)f1.y; wv0[6] = (bf16_t)f1.z; wv0[7] = (bf16_t)f1.w;
        wv1[0] = (bf16_t)f2.x; wv1[1] = (bf16_t)f2.y; wv1[2] = (bf16_t)f2.z; wv1[3] = (bf16_t)f2.w;
        wv1[4] = (bf16_t)f3.x; wv1[5] = (bf16_t)f3.y; wv1[6] = (bf16_t)f3.z; wv1[7] = (bf16_t)f3.w;
        *(bf16x8*)&Wl[ldst] = wv0;
        *(bf16x8*)&Wl[ldst + 8] = wv1;
        __syncthreads();
        if (it < 239) {                      // prefetch next tile (overlaps MFMA)
            const bf16_t* Ag2 = Ag + (it + 1) * 32;
            const float*  Wg2 = Wg + (it + 1) * 32;
            a0 = ((const uint4*)Ag2)[0]; a1 = ((const uint4*)Ag2)[1];
            f0 = ((const float4*)Wg2)[0]; f1 = ((const float4*)Wg2)[1];
            f2 = ((const float4*)Wg2)[2]; f3 = ((const float4*)Wg2)[3];
        }
        bf16x8 af0 = *(const bf16x8*)&Al[(mbase + lm) * 40 + lq * 8];
        bf16x8 af1 = *(const bf16x8*)&Al[(mbase + 16 + lm) * 40 + lq * 8];
        #pragma unroll
        for (int nt = 0; nt < 8; ++nt) {
            bf16x8 bfr = *(const bf16x8*)&Wl[(nt * 16 + lm) * 40 + lq * 8];
            acc[0][nt] = __builtin_amdgcn_mfma_f32_16x16x32_bf16(af0, bfr, acc[0][nt], 0, 0, 0);
            acc[1][nt] = __builtin_amdgcn_mfma_f32_16x16x32_bf16(af1, bfr, acc[1][nt], 0, 0, 0);
        }
    }

    // epilogue: C/D layout col=lane&15, row=(lane>>4)*4+reg  [m89-verified]
    float* pp = part + (size_t)ks * (B_ * NOUT);
    #pragma unroll
    for (int mt = 0; mt < 2; ++mt)
        #pragma unroll
        for (int nt = 0; nt < 8; ++nt)
            #pragma unroll
            for (int r = 0; r < 4; ++r) {
                int rr = mbase + mt * 16 + lq * 4 + r;
                int cc = n0 + nt * 16 + lm;
                pp[rr * NOUT + cc] = acc[mt][nt][r];
            }
}

// ---------------------------------------------------------------------------
// Kernel 5: reduce 4 k-split partials + readout_b -> y row-seg; then
// out[b][t*32+w] = sum_j y[b][t*512+j]*proj_w[w][j] + proj_b[w]
// grid 2048 = 128 b x 16 t
// ---------------------------------------------------------------------------
__global__ __launch_bounds__(256) void proj_kernel(const float* __restrict__ part,
                                                   const float* __restrict__ rb,
                                                   const float* __restrict__ pw,
                                                   const float* __restrict__ pb,
                                                   float* __restrict__ out) {
    __shared__ __align__(16) bf16_t pwl[512 * 32];  // transposed [j][w]
    __shared__ __align__(16) float yl[512];
    __shared__ float red[32 * 9];
    int tid = threadIdx.x;
    int b = blockIdx.x >> 4, t = blockIdx.x & 15;
    #pragma unroll
    for (int i = 0; i < 64; ++i) {
        int f = i * 256 + tid;          // flat index into proj_w [32][512]
        int w = f >> 9, j = f & 511;
        pwl[j * 32 + w] = (bf16_t)pw[f];
    }
    #pragma unroll
    for (int i = 0; i < 2; ++i) {
        int o = t * RES + i * 256 + tid;
        float v = rb[o];
        v += part[0 * (B_ * NOUT) + b * NOUT + o];
        v += part[1 * (B_ * NOUT) + b * NOUT + o];
        v += part[2 * (B_ * NOUT) + b * NOUT + o];
        v += part[3 * (B_ * NOUT) + b * NOUT + o];
        yl[i * 256 + tid] = v;
    }
    __syncthreads();
    int w = tid & 31, g = tid >> 5;
    float acc = 0.f;
    #pragma unroll 8
    for (int jj = 0; jj < 64; ++jj) {
        int j = g * 64 + jj;
        acc += yl[j] * (float)pwl[j * 32 + w];
    }
    red[w * 9 + g] = acc;
    __syncthreads();
    if (tid < 32) {
        float s = pb[tid];
        #pragma unroll
        for (int g2 = 0; g2 < 8; ++g2) s += red[tid * 9 + g2];
        out[b * 512 + t * 32 + tid] = s;
    }
}

// ---------------------------------------------------------------------------
// Workspace layout (bytes):
//   [0, 16MB)          : Xproj fp32 [128][64][512]   -- later REUSED as part
//                        part fp32 [4][128][8192] (written only after scan done)
//   [16MB, 16.5MB)     : Wpack bf16 [64][512][8]
//   [16.5MB, 24MB)     : Hout bf16 [128][30720]
// Total ~24 MB.
// ---------------------------------------------------------------------------
extern "C" void kernel_launch(void* const* d_in, const int* in_sizes, int n_in,
                              void* d_out, int out_size, void* d_ws, size_t ws_size,
                              hipStream_t stream) {
    const float* x    = (const float*)d_in[0];
    const float* Win  = (const float*)d_in[1];
    const float* Wres = (const float*)d_in[2];
    const float* Wro  = (const float*)d_in[3];
    const float* rb   = (const float*)d_in[4];
    const float* pw   = (const float*)d_in[5];
    const float* pb   = (const float*)d_in[6];
    float* out = (float*)d_out;

    char* ws = (char*)d_ws;
    float*  Xp   = (float*)ws;                          // 16 MB
    float*  part = (float*)ws;                          // reuses Xproj region
    bf16_t* Wp   = (bf16_t*)(ws + (16u << 20));         // 512 KB
    bf16_t* Hout = (bf16_t*)(ws + (16u << 20) + (1u << 19));  // 7.5 MB

    hipLaunchKernelGGL(wpack_kernel,   dim3(128),  dim3(256), 0, stream, Wres, Wp);
    hipLaunchKernelGGL(xproj_kernel,   dim3(512),  dim3(256), 0, stream, x, Win, Xp);
    hipLaunchKernelGGL(scan_kernel,    dim3(128),  dim3(256), 0, stream, Xp, Wp, Hout);
    hipLaunchKernelGGL(readout_kernel, dim3(256),  dim3(256), 0, stream, Hout, Wro, part);
    hipLaunchKernelGGL(proj_kernel,    dim3(2048), dim3(256), 0, stream, part, rb, pw, pb, out);
}